// Round 2
// baseline (2422.102 us; speedup 1.0000x reference)
//
#include <hip/hip_runtime.h>
#include <hip/hip_bf16.h>

typedef __hip_bfloat16 bf16;

__device__ __forceinline__ float b2f(bf16 v) { return __bfloat162float(v); }
__device__ __forceinline__ float lrelu(float x) { return x > 0.f ? x : 0.1f * x; }
// dtype-agnostic element load: f32 flag chooses float vs bf16 decode
__device__ __forceinline__ float ldE(const void* p, long i, int f32) {
    return f32 ? ((const float*)p)[i] : __bfloat162float(((const bf16*)p)[i]);
}

// ---------------- workspace layout (floats) ----------------
// qw1[64]      @ 0
// qw2[768]     @ 64
// qw3[2560]    @ 832
// qw4[5120]    @ 3392
// qwdT[55296]  @ 8512   (transposed: [864][64])
// qwo[64]      @ 63808
// fb1[16]      @ 63872
// fb2[16]      @ 63888
// fb3[32]      @ 63904
// fb4[32]      @ 63936
// fbd[64]      @ 63968
// fbo[1]       @ 64032
// dtype flag   @ int index 64036
// total < 64040 floats = 256160 B

// Decide whether buffers are f32 or bf16 by reading x's first 2048 halfwords
// as bf16. True bf16 N(0,1) data never has |v| >= 2^20; f32 data read this
// way has ~21% of elements with huge/NaN exponents (uniform low halves).
__global__ void __launch_bounds__(256) detect_dtype(
    const unsigned short* __restrict__ x, int* __restrict__ flag)
{
    __shared__ int cnt;
    if (threadIdx.x == 0) cnt = 0;
    __syncthreads();
    int w = 0;
    for (int i = threadIdx.x; i < 2048; i += 256) {
        int e = (x[i] >> 7) & 0xFF;          // bf16 exponent field
        if (e >= 147) w = 1;                 // |v| >= 2^20 -> not genuine bf16
    }
    atomicAdd(&cnt, w);
    __syncthreads();
    if (threadIdx.x == 0) flag[0] = (cnt > 4) ? 1 : 0;
}

__global__ void __launch_bounds__(256) quant_prep(
    const void* __restrict__ w1, const void* __restrict__ w2,
    const void* __restrict__ w3, const void* __restrict__ w4,
    const void* __restrict__ wd, const void* __restrict__ wo,
    const void* __restrict__ b1, const void* __restrict__ b2,
    const void* __restrict__ b3, const void* __restrict__ b4,
    const void* __restrict__ bd, const void* __restrict__ bo,
    float* __restrict__ ws, const int* __restrict__ flagp)
{
    const int f32 = flagp[0];
    int tid = threadIdx.x;
    int which = blockIdx.x;
    if (which == 6) {
        // bias conversions (not quantized in reference)
        if (tid < 16)        ws[63872 + tid]       = ldE(b1, tid, f32);
        else if (tid < 32)   ws[63888 + tid - 16]  = ldE(b2, tid - 16, f32);
        else if (tid < 64)   ws[63904 + tid - 32]  = ldE(b3, tid - 32, f32);
        else if (tid < 96)   ws[63936 + tid - 64]  = ldE(b4, tid - 64, f32);
        else if (tid < 160)  ws[63968 + tid - 96]  = ldE(bd, tid - 96, f32);
        else if (tid == 160) ws[64032]             = ldE(bo, 0, f32);
        return;
    }
    const void* src; float* dst; int n; bool tr = false;
    switch (which) {
        case 0:  src = w1; dst = ws + 0;     n = 64;    break;
        case 1:  src = w2; dst = ws + 64;    n = 768;   break;
        case 2:  src = w3; dst = ws + 832;   n = 2560;  break;
        case 3:  src = w4; dst = ws + 3392;  n = 5120;  break;
        case 4:  src = wd; dst = ws + 8512;  n = 55296; tr = true; break;
        default: src = wo; dst = ws + 63808; n = 64;    break;
    }
    __shared__ float red[256];
    float m = 0.f;
    for (int i = tid; i < n; i += 256) m = fmaxf(m, fabsf(ldE(src, i, f32)));
    red[tid] = m;
    __syncthreads();
    for (int s = 128; s > 0; s >>= 1) {
        if (tid < s) red[tid] = fmaxf(red[tid], red[tid + s]);
        __syncthreads();
    }
    float sc = red[0] / 127.f;   // exact division, matches np max|w|/127
    for (int i = tid; i < n; i += 256) {
        float w = ldE(src, i, f32);
        float q = rintf(w / sc);                     // round-half-even like jnp.round
        q = fminf(127.f, fmaxf(-127.f, q)) * sc;     // clip then dequant
        int di;
        if (tr) { int o = i / 864; int j = i - o * 864; di = j * 64 + o; }
        else    { di = i; }
        dst[di] = q;
    }
}

// One wave computes 4 consecutive output channels (co0..co0+3) for up to 64
// positions (one per lane). co0 is wave-uniform -> weight/bias loads are
// scalar (s_load); only activation reads hit the LDS pipe (K reads feed
// 4*K FMAs). OOB lanes compute garbage but never store; LDS buffers are
// padded to 2048 so garbage reads stay in bounds.
template<int CIN, int K>
__device__ __forceinline__ void conv_task(
    const float* __restrict__ in, int inStride,
    const float* __restrict__ wq,     // [CO][CIN][K] quantized, global
    const float* __restrict__ bias,   // [CO] global (f32)
    int co0, int pos, int validL,
    float* __restrict__ out, int outStride)
{
    float acc0 = bias[co0 + 0];
    float acc1 = bias[co0 + 1];
    float acc2 = bias[co0 + 2];
    float acc3 = bias[co0 + 3];
#pragma unroll
    for (int ci = 0; ci < CIN; ++ci) {
        float a[K];
#pragma unroll
        for (int k = 0; k < K; ++k) a[k] = in[ci * inStride + pos + k];
        const float* w = wq + (co0 * CIN + ci) * K;
#pragma unroll
        for (int k = 0; k < K; ++k) {
            acc0 = fmaf(a[k], w[k], acc0);
            acc1 = fmaf(a[k], w[CIN * K + k], acc1);
            acc2 = fmaf(a[k], w[2 * CIN * K + k], acc2);
            acc3 = fmaf(a[k], w[3 * CIN * K + k], acc3);
        }
    }
    if (pos < validL) {
        out[(co0 + 0) * outStride + pos] = lrelu(acc0);
        out[(co0 + 1) * outStride + pos] = lrelu(acc1);
        out[(co0 + 2) * outStride + pos] = lrelu(acc2);
        out[(co0 + 3) * outStride + pos] = lrelu(acc3);
    }
}

__global__ void __launch_bounds__(256) qcnn_main(
    const void* __restrict__ x,      // [B][2][128] f32 or bf16
    const float* __restrict__ ws,    // quantized weights + f32 biases
    void* __restrict__ out,          // [B] f32 or bf16
    const int* __restrict__ flagp)
{
    const int f32 = flagp[0];
    const float* qw1  = ws;
    const float* qw2  = ws + 64;
    const float* qw3  = ws + 832;
    const float* qw4  = ws + 3392;
    const float* qwdT = ws + 8512;
    const float* qwo  = ws + 63808;
    const float* fb1  = ws + 63872;
    const float* fb2  = ws + 63888;
    const float* fb3  = ws + 63904;
    const float* fb4  = ws + 63936;
    const float* fbd  = ws + 63968;

    __shared__ float xb[264];
    __shared__ float bufA[2048];
    __shared__ float bufB[2048];
    __shared__ __attribute__((aligned(16))) float flatb[8][864];

    int tid  = threadIdx.x;
    int lane = tid & 63;
    int wave = __builtin_amdgcn_readfirstlane(tid >> 6);
    long b0  = (long)blockIdx.x * 8;

    for (int s = 0; s < 8; ++s) {
        __syncthreads();   // previous sample's readers of xb/bufA done
        xb[tid] = ldE(x, (b0 + s) * 256 + tid, f32);
        __syncthreads();
        // conv1: [2][128] -> [16][127]
#pragma unroll
        for (int rep = 0; rep < 2; ++rep) {
            int t = wave + 4 * rep;
            conv_task<2, 2>(xb, 128, qw1, fb1, (t & 3) * 4, (t >> 2) * 64 + lane, 127, bufA, 127);
        }
        __syncthreads();
        // conv2: [16][127] -> [16][125]
#pragma unroll
        for (int rep = 0; rep < 2; ++rep) {
            int t = wave + 4 * rep;
            conv_task<16, 3>(bufA, 127, qw2, fb2, (t & 3) * 4, (t >> 2) * 64 + lane, 125, bufB, 125);
        }
        __syncthreads();
        // pool1: [16][125] -> [16][62]
        for (int idx = tid; idx < 16 * 62; idx += 256) {
            int c = idx / 62, i = idx - c * 62;
            bufA[c * 62 + i] = fmaxf(bufB[c * 125 + 2 * i], bufB[c * 125 + 2 * i + 1]);
        }
        __syncthreads();
        // conv3: [16][62] -> [32][58]
#pragma unroll
        for (int rep = 0; rep < 2; ++rep) {
            int t = wave + 4 * rep;
            conv_task<16, 5>(bufA, 62, qw3, fb3, t * 4, lane, 58, bufB, 58);
        }
        __syncthreads();
        // conv4: [32][58] -> [32][54]
#pragma unroll
        for (int rep = 0; rep < 2; ++rep) {
            int t = wave + 4 * rep;
            conv_task<32, 5>(bufB, 58, qw4, fb4, t * 4, lane, 54, bufA, 54);
        }
        __syncthreads();
        // pool2 + flatten: [32][54] -> flat[s][864]
        for (int idx = tid; idx < 32 * 27; idx += 256) {
            int c = idx / 27, i = idx - c * 27;
            flatb[s][c * 27 + i] = fmaxf(bufA[c * 54 + 2 * i], bufA[c * 54 + 2 * i + 1]);
        }
    }
    __syncthreads();

    // dense: [8][864] @ wdT[864][64] -> [8][64]; each wave owns a j-quarter,
    // weight vector loaded once per j and applied to all 8 samples.
    int o = tid & 63, jq = tid >> 6;
    float acc[8];
#pragma unroll
    for (int s = 0; s < 8; ++s) acc[s] = 0.f;
    for (int j = jq * 216; j < jq * 216 + 216; j += 4) {
        float w0 = qwdT[(j + 0) * 64 + o];
        float w1 = qwdT[(j + 1) * 64 + o];
        float w2 = qwdT[(j + 2) * 64 + o];
        float w3 = qwdT[(j + 3) * 64 + o];
#pragma unroll
        for (int s = 0; s < 8; ++s) {
            const float4 f = *(const float4*)&flatb[s][j];   // uniform b128 broadcast
            acc[s] = fmaf(f.x, w0, acc[s]);
            acc[s] = fmaf(f.y, w1, acc[s]);
            acc[s] = fmaf(f.z, w2, acc[s]);
            acc[s] = fmaf(f.w, w3, acc[s]);
        }
    }
    __syncthreads();   // conv-stage readers of bufB are long done
#pragma unroll
    for (int s = 0; s < 8; ++s) bufB[jq * 512 + s * 64 + o] = acc[s];
    __syncthreads();
    // reduce quarters + bias + lrelu -> bufA[s*64+o]
    for (int p = tid; p < 512; p += 256) {
        int ss = p >> 6, oo = p & 63;
        float v = fbd[oo] + bufB[ss * 64 + oo] + bufB[512 + ss * 64 + oo]
                + bufB[1024 + ss * 64 + oo] + bufB[1536 + ss * 64 + oo];
        bufA[ss * 64 + oo] = lrelu(v);
    }
    __syncthreads();
    // output head: y[s] = bo + hd[s] . qwo
    if (tid < 8) {
        float y = ws[64032];
        for (int oo = 0; oo < 64; ++oo) y += bufA[tid * 64 + oo] * qwo[oo];
        if (f32) ((float*)out)[b0 + tid] = y;
        else     ((bf16*)out)[b0 + tid] = __float2bfloat16(y);
    }
}

extern "C" void kernel_launch(void* const* d_in, const int* in_sizes, int n_in,
                              void* d_out, int out_size, void* d_ws, size_t ws_size,
                              hipStream_t stream) {
    const void* x  = d_in[0];
    const void* w1 = d_in[1];
    const void* b1 = d_in[2];
    const void* w2 = d_in[3];
    const void* b2 = d_in[4];
    const void* w3 = d_in[5];
    const void* b3 = d_in[6];
    const void* w4 = d_in[7];
    const void* b4 = d_in[8];
    const void* wd = d_in[9];
    const void* bd = d_in[10];
    const void* wo = d_in[11];
    const void* bo = d_in[12];
    float* ws = (float*)d_ws;
    int* flag = ((int*)d_ws) + 64036;

    int B = in_sizes[0] / 256;            // 32768
    detect_dtype<<<1, 256, 0, stream>>>((const unsigned short*)x, flag);
    quant_prep<<<7, 256, 0, stream>>>(w1, w2, w3, w4, wd, wo,
                                      b1, b2, b3, b4, bd, bo, ws, flag);
    qcnn_main<<<B / 8, 256, 0, stream>>>(x, ws, d_out, flag);
}

// Round 3
// 308.356 us; speedup vs baseline: 7.8549x; 7.8549x over previous
//
#include <hip/hip_runtime.h>
#include <hip/hip_bf16.h>

typedef __hip_bfloat16 bf16;
typedef _Float16 h16;
typedef __attribute__((ext_vector_type(8))) _Float16 h16x8;
typedef __attribute__((ext_vector_type(4))) float f32x4;
typedef __attribute__((ext_vector_type(16))) float f32x16;

__device__ __forceinline__ float lrelu(float x) { return x > 0.f ? x : 0.1f * x; }
// dtype-agnostic element load: f32 flag chooses float vs bf16 decode
__device__ __forceinline__ float ldE(const void* p, long i, int f32) {
    return f32 ? ((const float*)p)[i] : __bfloat162float(((const bf16*)p)[i]);
}
__device__ __forceinline__ uint2 pack4(float a, float b, float c, float d) {
    union { _Float16 h[4]; uint2 u; } t;
    t.h[0] = (_Float16)a; t.h[1] = (_Float16)b; t.h[2] = (_Float16)c; t.h[3] = (_Float16)d;
    return t.u;
}
#define LDS_FENCE() asm volatile("s_waitcnt lgkmcnt(0)" ::: "memory")

// ---------------- workspace layout ----------------
// float region (wsf):
//   [0..63]    qw1f      quantized conv1 weights, plain [co][ci][k]
//   [64..79]   fb1   [80..95] fb2   [96..127] fb3   [128..159] fb4
//   [160..223] fbd   [224..287] qwo(quantized f32)   [288] fbo
//   [290]      dtype flag (int)
// f16 frag region (wh = (h16*)(wsf+292)), exact MFMA A-fragment order:
//   F2 @ 0     : conv2  2 chunks x 64 lanes x 8   (16x16x32, K=48 padded to 64)
//   F3 @ 1024  : conv3  5 chunks x 64 x 8         (32x32x16, K=80)
//   F4 @ 3584  : conv4 10 chunks x 64 x 8         (32x32x16, K=160)
//   FD @ 8704  : dense  4 mt x 27 chunks x 64 x 8 (16x16x32, K=864)

__global__ void __launch_bounds__(256) detect_dtype(
    const unsigned short* __restrict__ x, int* __restrict__ flag)
{
    __shared__ int cnt;
    if (threadIdx.x == 0) cnt = 0;
    __syncthreads();
    int w = 0;
    for (int i = threadIdx.x; i < 2048; i += 256) {
        int e = (x[i] >> 7) & 0xFF;          // bf16 exponent field
        if (e >= 147) w = 1;                 // |v| >= 2^20 -> not genuine bf16
    }
    atomicAdd(&cnt, w);
    __syncthreads();
    if (threadIdx.x == 0) flag[0] = (cnt > 4) ? 1 : 0;
}

__device__ __forceinline__ float qv(const void* src, int idx, float sc, int f32) {
    float w = ldE(src, idx, f32);
    float q = rintf(w / sc);                    // round-half-even like jnp.round
    return fminf(127.f, fmaxf(-127.f, q)) * sc; // clip then dequant
}

__global__ void __launch_bounds__(256) quant_prep(
    const void* __restrict__ w1, const void* __restrict__ w2,
    const void* __restrict__ w3, const void* __restrict__ w4,
    const void* __restrict__ wd, const void* __restrict__ wo,
    const void* __restrict__ b1, const void* __restrict__ b2,
    const void* __restrict__ b3, const void* __restrict__ b4,
    const void* __restrict__ bd, const void* __restrict__ bo,
    float* __restrict__ wsf, const int* __restrict__ flagp)
{
    const int f32 = flagp[0];
    h16* wh = (h16*)(wsf + 292);
    int tid = threadIdx.x;
    int which = blockIdx.x;
    if (which == 6) {
        if (tid < 16)        wsf[64 + tid]        = ldE(b1, tid, f32);
        else if (tid < 32)   wsf[80 + tid - 16]   = ldE(b2, tid - 16, f32);
        else if (tid < 64)   wsf[96 + tid - 32]   = ldE(b3, tid - 32, f32);
        else if (tid < 96)   wsf[128 + tid - 64]  = ldE(b4, tid - 64, f32);
        else if (tid < 160)  wsf[160 + tid - 96]  = ldE(bd, tid - 96, f32);
        else if (tid == 160) wsf[288]             = ldE(bo, 0, f32);
        return;
    }
    const void* src; int n;
    switch (which) {
        case 0:  src = w1; n = 64;    break;
        case 1:  src = w2; n = 768;   break;
        case 2:  src = w3; n = 2560;  break;
        case 3:  src = w4; n = 5120;  break;
        case 4:  src = wd; n = 55296; break;
        default: src = wo; n = 64;    break;
    }
    __shared__ float red[256];
    float m = 0.f;
    for (int i = tid; i < n; i += 256) m = fmaxf(m, fabsf(ldE(src, i, f32)));
    red[tid] = m;
    __syncthreads();
    for (int s = 128; s > 0; s >>= 1) {
        if (tid < s) red[tid] = fmaxf(red[tid], red[tid + s]);
        __syncthreads();
    }
    float sc = red[0] / 127.f;

    if (which == 0) {                       // conv1: plain f32
        if (tid < 64) wsf[tid] = qv(src, tid, sc, f32);
    } else if (which == 5) {                // wo: plain f32 (quantized)
        if (tid < 64) wsf[224 + tid] = qv(src, tid, sc, f32);
    } else if (which == 1) {                // conv2 frags: K order k=dk*16+ci, pad dk=3 with 0
        for (int e = tid; e < 1024; e += 256) {
            int c = e >> 9, l = (e >> 3) & 63, j = e & 7;
            int mm = l & 15;
            int k = c * 32 + ((l >> 4) & 3) * 8 + j;
            int dk = k >> 4, ci = k & 15;
            float v = (dk < 3) ? qv(src, (mm * 16 + ci) * 3 + dk, sc, f32) : 0.f;
            wh[0 + e] = (h16)v;
        }
    } else if (which == 2) {                // conv3 frags: K=80, k=dk*16+ci
        for (int e = tid; e < 2560; e += 256) {
            int c = e >> 9, l = (e >> 3) & 63, j = e & 7;
            int mm = l & 31;
            int ci = ((l >> 5) & 1) * 8 + j;     // k_local, dk = c
            float v = qv(src, (mm * 16 + ci) * 5 + c, sc, f32);
            wh[1024 + e] = (h16)v;
        }
    } else if (which == 3) {                // conv4 frags: K=160, k=dk*32+ci
        for (int e = tid; e < 5120; e += 256) {
            int c = e >> 9, l = (e >> 3) & 63, j = e & 7;
            int mm = l & 31;
            int k = c * 16 + ((l >> 5) & 1) * 8 + j;
            int dk = k >> 5, ci = k & 31;
            float v = qv(src, (mm * 32 + ci) * 5 + dk, sc, f32);
            wh[3584 + e] = (h16)v;
        }
    } else {                                // dense frags: K=864, k=i*32+cch (our flat order)
        for (int e = tid; e < 55296; e += 256) {
            int j = e & 7, l = (e >> 3) & 63, t = e >> 9;     // t = mt*27 + c
            int mt = t / 27, c = t - mt * 27;
            int o = mt * 16 + (l & 15);
            int k = c * 32 + ((l >> 4) & 3) * 8 + j;
            int i = k >> 5, cch = k & 31;
            float v = qv(src, o * 864 + cch * 27 + i, sc, f32);
            wh[8704 + e] = (h16)v;
        }
    }
}

__global__ void __launch_bounds__(256, 3) qcnn_main(
    const void* __restrict__ x,      // [B][2][128] f32 or bf16
    const float* __restrict__ wsf,
    void* __restrict__ out,          // [B]
    const int* __restrict__ flagp)
{
    const int f32flag = flagp[0];
    const float* qw1f = wsf;
    const float* fb1g = wsf + 64;
    const h16*  wh  = (const h16*)(wsf + 292);
    const h16*  F2g = wh;
    const h16*  F3g = wh + 1024;
    const h16*  F4g = wh + 3584;
    const h16*  FDg = wh + 8704;

    // per-wave activation buffers (f16, [pos][chan] rows)
    __shared__ __align__(16) h16 Uall[4][2096];   // 131 rows x 16ch  (act1/pooled/act4)
    __shared__ __align__(16) h16 Vall[4][2176];   // 68 rows x 32ch   (act2[125][16]/act3)
    __shared__ __align__(16) h16 flatb[8][864];
    __shared__ float red[256];

    int tid  = threadIdx.x;
    int lane = tid & 63;
    int w    = __builtin_amdgcn_readfirstlane(tid >> 6);
    int n16  = lane & 15, kg16 = (lane >> 4) & 3;
    int n32  = lane & 31, kg32 = (lane >> 5) & 1;
    int o16  = kg16 * 4;                    // 16x16 C/D row base
    h16* U = Uall[w];
    h16* V = Vall[w];
    long b0 = (long)blockIdx.x * 8;

    // Preload A fragments (coalesced 16B/lane, loop-invariant)
    h16x8 a2[2], a3[5], a4[10];
#pragma unroll
    for (int c = 0; c < 2; ++c)  a2[c] = *(const h16x8*)&F2g[c * 512 + lane * 8];
#pragma unroll
    for (int c = 0; c < 5; ++c)  a3[c] = *(const h16x8*)&F3g[c * 512 + lane * 8];
#pragma unroll
    for (int c = 0; c < 10; ++c) a4[c] = *(const h16x8*)&F4g[c * 512 + lane * 8];
    f32x4 b2v = *(const f32x4*)&wsf[80 + o16];   // conv2 bias for this lane's rows

    for (int it = 0; it < 2; ++it) {
        int slot = w * 2 + it;
        long sb = (b0 + slot) * 256;

        // ---- conv1 (VALU): x[2][128] -> act1 U[127][16], rows 127..130 zeroed ----
        LDS_FENCE();
        float xl[2][4];
#pragma unroll
        for (int ci = 0; ci < 2; ++ci) {
            int rb = ci * 128;
            xl[ci][0] = ldE(x, sb + rb + lane, f32flag);
            xl[ci][1] = ldE(x, sb + rb + lane + 1, f32flag);
            xl[ci][2] = ldE(x, sb + rb + 64 + lane, f32flag);
            xl[ci][3] = ldE(x, sb + rb + 64 + ((lane + 1) & 63), f32flag);
        }
        h16x8 ra, rbv, rc, rd;
#pragma unroll
        for (int co = 0; co < 16; ++co) {
            float w00 = qw1f[co*4+0], w01 = qw1f[co*4+1], w10 = qw1f[co*4+2], w11 = qw1f[co*4+3];
            float bb = fb1g[co];
            float v0 = bb + xl[0][0]*w00 + xl[0][1]*w01 + xl[1][0]*w10 + xl[1][1]*w11;
            float v1 = bb + xl[0][2]*w00 + xl[0][3]*w01 + xl[1][2]*w10 + xl[1][3]*w11;
            v0 = lrelu(v0); v1 = lrelu(v1);
            if (co < 8) { ra[co] = (h16)v0; rc[co] = (h16)v1; }
            else        { rbv[co-8] = (h16)v0; rd[co-8] = (h16)v1; }
        }
        *(h16x8*)&U[lane * 16]     = ra;
        *(h16x8*)&U[lane * 16 + 8] = rbv;
        if (lane < 63) {
            *(h16x8*)&U[(64 + lane) * 16]     = rc;
            *(h16x8*)&U[(64 + lane) * 16 + 8] = rd;
        }
        if (lane < 8) {   // zero K-pad rows (prevents NaN*0 through zero A rows)
            h16x8 z = {(h16)0.f,(h16)0.f,(h16)0.f,(h16)0.f,(h16)0.f,(h16)0.f,(h16)0.f,(h16)0.f};
            *(h16x8*)&U[(127 + (lane >> 1)) * 16 + (lane & 1) * 8] = z;
        }
        LDS_FENCE();

        // ---- conv2 (16x16x32): act1 U[127][16] -> act2 V[125][16] ----
#pragma unroll
        for (int t = 0; t < 8; ++t) {
            int n = t * 16 + n16;
            f32x4 acc = {0.f, 0.f, 0.f, 0.f};
#pragma unroll
            for (int c = 0; c < 2; ++c) {
                int k0 = c * 32 + kg16 * 8;
                h16x8 bfr = *(const h16x8*)&U[(n + (k0 >> 4)) * 16 + (k0 & 15)];
                acc = __builtin_amdgcn_mfma_f32_16x16x32_f16(a2[c], bfr, acc, 0, 0, 0);
            }
            if (n < 125) {
                uint2 p = pack4(lrelu(acc[0] + b2v[0]), lrelu(acc[1] + b2v[1]),
                                lrelu(acc[2] + b2v[2]), lrelu(acc[3] + b2v[3]));
                *(uint2*)&V[n * 16 + o16] = p;
            }
        }
        LDS_FENCE();

        // ---- pool1 (f16 exact): act2 V[125][16] -> pooled U[62][16] ----
        if (lane < 62) {
            h16x8 p00 = *(const h16x8*)&V[(2 * lane) * 16];
            h16x8 p01 = *(const h16x8*)&V[(2 * lane) * 16 + 8];
            h16x8 p10 = *(const h16x8*)&V[(2 * lane + 1) * 16];
            h16x8 p11 = *(const h16x8*)&V[(2 * lane + 1) * 16 + 8];
            h16x8 m0, m1;
#pragma unroll
            for (int e = 0; e < 8; ++e) {
                m0[e] = p00[e] > p10[e] ? p00[e] : p10[e];
                m1[e] = p01[e] > p11[e] ? p01[e] : p11[e];
            }
            *(h16x8*)&U[lane * 16]     = m0;
            *(h16x8*)&U[lane * 16 + 8] = m1;
        }
        LDS_FENCE();

        // ---- conv3 (32x32x16): pooled U[62][16] -> act3 V[58][32] ----
#pragma unroll
        for (int t = 0; t < 2; ++t) {
            int n = t * 32 + n32;
            f32x16 acc = {0.f,0.f,0.f,0.f,0.f,0.f,0.f,0.f,0.f,0.f,0.f,0.f,0.f,0.f,0.f,0.f};
#pragma unroll
            for (int c = 0; c < 5; ++c) {
                h16x8 bfr = *(const h16x8*)&U[(n + c) * 16 + kg32 * 8];
                acc = __builtin_amdgcn_mfma_f32_32x32x16_f16(a3[c], bfr, acc, 0, 0, 0);
            }
#pragma unroll
            for (int g = 0; g < 4; ++g) {
                int r0 = 8 * g + 4 * kg32;
                f32x4 bv = *(const f32x4*)&wsf[96 + r0];
                if (n < 58) {
                    uint2 p = pack4(lrelu(acc[4*g+0] + bv[0]), lrelu(acc[4*g+1] + bv[1]),
                                    lrelu(acc[4*g+2] + bv[2]), lrelu(acc[4*g+3] + bv[3]));
                    *(uint2*)&V[n * 32 + r0] = p;
                }
            }
        }
        LDS_FENCE();

        // ---- conv4 (32x32x16): act3 V[58][32] -> act4 U[54][32] ----
#pragma unroll
        for (int t = 0; t < 2; ++t) {
            int n = t * 32 + n32;
            f32x16 acc = {0.f,0.f,0.f,0.f,0.f,0.f,0.f,0.f,0.f,0.f,0.f,0.f,0.f,0.f,0.f,0.f};
#pragma unroll
            for (int c = 0; c < 10; ++c) {
                int k0 = c * 16 + kg32 * 8;
                h16x8 bfr = *(const h16x8*)&V[(n + (k0 >> 5)) * 32 + (k0 & 31)];
                acc = __builtin_amdgcn_mfma_f32_32x32x16_f16(a4[c], bfr, acc, 0, 0, 0);
            }
#pragma unroll
            for (int g = 0; g < 4; ++g) {
                int r0 = 8 * g + 4 * kg32;
                f32x4 bv = *(const f32x4*)&wsf[128 + r0];
                if (n < 54) {
                    uint2 p = pack4(lrelu(acc[4*g+0] + bv[0]), lrelu(acc[4*g+1] + bv[1]),
                                    lrelu(acc[4*g+2] + bv[2]), lrelu(acc[4*g+3] + bv[3]));
                    *(uint2*)&U[n * 32 + r0] = p;
                }
            }
        }
        LDS_FENCE();

        // ---- pool2 + flatten (f16 exact): act4 U[54][32] -> flatb[slot][i*32+c] ----
        if (lane < 27) {
#pragma unroll
            for (int hq = 0; hq < 4; ++hq) {
                h16x8 pa = *(const h16x8*)&U[(2 * lane) * 32 + hq * 8];
                h16x8 pb = *(const h16x8*)&U[(2 * lane + 1) * 32 + hq * 8];
                h16x8 mm;
#pragma unroll
                for (int e = 0; e < 8; ++e) mm[e] = pa[e] > pb[e] ? pa[e] : pb[e];
                *(h16x8*)&flatb[slot][lane * 32 + hq * 8] = mm;
            }
        }
    }
    __syncthreads();

    // ---- dense (16x16x32): flatb[8][864] @ FD -> h[64][16], wave w = m-tile ----
    f32x4 dacc = {0.f, 0.f, 0.f, 0.f};
    for (int c = 0; c < 27; ++c) {
        h16x8 aw = *(const h16x8*)&FDg[((w * 27 + c) * 64 + lane) * 8];
        h16x8 bh = *(const h16x8*)&flatb[lane & 7][c * 32 + kg16 * 8];
        dacc = __builtin_amdgcn_mfma_f32_16x16x32_f16(aw, bh, dacc, 0, 0, 0);
    }
    // head: partial = sum_reg lrelu(h+bd)*qwo
    int o0g = w * 16 + o16;
    f32x4 bdv = *(const f32x4*)&wsf[160 + o0g];
    f32x4 qov = *(const f32x4*)&wsf[224 + o0g];
    float part = 0.f;
#pragma unroll
    for (int q = 0; q < 4; ++q) part += lrelu(dacc[q] + bdv[q]) * qov[q];
    red[tid] = part;
    __syncthreads();
    if (tid < 8) {
        float y = wsf[288];
#pragma unroll
        for (int g = 0; g < 16; ++g) y += red[(g >> 2) * 64 + (g & 3) * 16 + tid];
        if (f32flag) ((float*)out)[b0 + tid] = y;
        else         ((bf16*)out)[b0 + tid] = __float2bfloat16(y);
    }
}

extern "C" void kernel_launch(void* const* d_in, const int* in_sizes, int n_in,
                              void* d_out, int out_size, void* d_ws, size_t ws_size,
                              hipStream_t stream) {
    const void* x  = d_in[0];
    const void* w1 = d_in[1];
    const void* b1 = d_in[2];
    const void* w2 = d_in[3];
    const void* b2 = d_in[4];
    const void* w3 = d_in[5];
    const void* b3 = d_in[6];
    const void* w4 = d_in[7];
    const void* b4 = d_in[8];
    const void* wd = d_in[9];
    const void* bd = d_in[10];
    const void* wo = d_in[11];
    const void* bo = d_in[12];
    float* wsf = (float*)d_ws;
    int* flag = ((int*)d_ws) + 290;

    int B = in_sizes[0] / 256;            // 32768
    detect_dtype<<<1, 256, 0, stream>>>((const unsigned short*)x, flag);
    quant_prep<<<7, 256, 0, stream>>>(w1, w2, w3, w4, wd, wo,
                                      b1, b2, b3, b4, bd, bo, wsf, flag);
    qcnn_main<<<B / 8, 256, 0, stream>>>(x, wsf, d_out, flag);
}

// Round 4
// 209.785 us; speedup vs baseline: 11.5457x; 1.4699x over previous
//
#include <hip/hip_runtime.h>
#include <hip/hip_bf16.h>

typedef __hip_bfloat16 bf16;
typedef _Float16 h16;
typedef __attribute__((ext_vector_type(8))) _Float16 h16x8;
typedef __attribute__((ext_vector_type(4))) float f32x4;
typedef __attribute__((ext_vector_type(16))) float f32x16;

__device__ __forceinline__ float lrelu(float x) { return x > 0.f ? x : 0.1f * x; }
__device__ __forceinline__ float ldE(const void* p, long i, int f32) {
    return f32 ? ((const float*)p)[i] : __bfloat162float(((const bf16*)p)[i]);
}
__device__ __forceinline__ uint2 pack4(float a, float b, float c, float d) {
    union { _Float16 h[4]; uint2 u; } t;
    t.h[0] = (_Float16)a; t.h[1] = (_Float16)b; t.h[2] = (_Float16)c; t.h[3] = (_Float16)d;
    return t.u;
}
#define LDS_FENCE() asm volatile("s_waitcnt lgkmcnt(0)" ::: "memory")

// ---------------- workspace layout ----------------
// float region (wsf):
//   [0..63] qw1f  [64..79] fb1 [80..95] fb2 [96..127] fb3 [128..159] fb4
//   [160..223] fbd [224..287] qwo [288] fbo   int flag @ index 290
// f16 frag region wh = (h16*)(wsf+292):
//   F2 @0 (1024), F3 @1024 (2560), F4 @3584 (5120), FD @8704 (55296)

__device__ __forceinline__ float qv(const void* src, int idx, float sc, int f32) {
    float w = ldE(src, idx, f32);
    float q = rintf(w / sc);                    // round-half-even like jnp.round
    return fminf(127.f, fmaxf(-127.f, q)) * sc; // clip then dequant
}

// grid = 54: blocks 0..47 dense frag slices (redundant scale), 48..52 small
// weight tensors, 53 biases. Every block also computes the f32-vs-bf16 flag
// from x (identical result, benign duplicate store).
__global__ void __launch_bounds__(256) quant_prep(
    const unsigned short* __restrict__ xu,
    const void* __restrict__ w1, const void* __restrict__ w2,
    const void* __restrict__ w3, const void* __restrict__ w4,
    const void* __restrict__ wd, const void* __restrict__ wo,
    const void* __restrict__ b1, const void* __restrict__ b2,
    const void* __restrict__ b3, const void* __restrict__ b4,
    const void* __restrict__ bd, const void* __restrict__ bo,
    float* __restrict__ wsf)
{
    int tid = threadIdx.x;
    int which = blockIdx.x;
    __shared__ float red[256];
    __shared__ int cnt;
    // ---- dtype detect (first 2048 halfwords of x read as bf16) ----
    if (tid == 0) cnt = 0;
    __syncthreads();
    int bad = 0;
    for (int i = tid; i < 2048; i += 256) {
        int e = (xu[i] >> 7) & 0xFF;
        if (e >= 147) bad = 1;      // |v| >= 2^20: not genuine bf16 data
    }
    atomicAdd(&cnt, bad);
    __syncthreads();
    const int f32 = (cnt > 4) ? 1 : 0;
    if (tid == 0) ((int*)wsf)[290] = f32;

    h16* wh = (h16*)(wsf + 292);

    if (which == 53) {   // biases (not quantized)
        if (tid < 16)        wsf[64 + tid]        = ldE(b1, tid, f32);
        else if (tid < 32)   wsf[80 + tid - 16]   = ldE(b2, tid - 16, f32);
        else if (tid < 64)   wsf[96 + tid - 32]   = ldE(b3, tid - 32, f32);
        else if (tid < 96)   wsf[128 + tid - 64]  = ldE(b4, tid - 64, f32);
        else if (tid < 160)  wsf[160 + tid - 96]  = ldE(bd, tid - 96, f32);
        else if (tid == 160) wsf[288]             = ldE(bo, 0, f32);
        return;
    }

    if (which < 48) {
        // ---- dense: redundant coalesced scale, then a 1152-elem frag slice ----
        float m0 = 0.f, m1 = 0.f, m2 = 0.f, m3 = 0.f;
        for (int i = tid; i < 55296; i += 1024) {   // 54 exact iterations
            m0 = fmaxf(m0, fabsf(ldE(wd, i, f32)));
            m1 = fmaxf(m1, fabsf(ldE(wd, i + 256, f32)));
            m2 = fmaxf(m2, fabsf(ldE(wd, i + 512, f32)));
            m3 = fmaxf(m3, fabsf(ldE(wd, i + 768, f32)));
        }
        red[tid] = fmaxf(fmaxf(m0, m1), fmaxf(m2, m3));
        __syncthreads();
        for (int s = 128; s > 0; s >>= 1) {
            if (tid < s) red[tid] = fmaxf(red[tid], red[tid + s]);
            __syncthreads();
        }
        float sc = red[0] / 127.f;
        int e1 = (which + 1) * 1152;
        for (int e = which * 1152 + tid; e < e1; e += 256) {
            int j = e & 7, l = (e >> 3) & 63, t = e >> 9;   // t = mt*27 + c
            int mt = t / 27, c = t - mt * 27;
            int o = mt * 16 + (l & 15);
            int k = c * 32 + ((l >> 4) & 3) * 8 + j;
            int i = k >> 5, cch = k & 31;
            wh[8704 + e] = (h16)qv(wd, o * 864 + cch * 27 + i, sc, f32);
        }
        return;
    }

    // ---- small tensors ----
    const void* src; int n;
    switch (which) {
        case 48: src = w1; n = 64;   break;
        case 49: src = w2; n = 768;  break;
        case 50: src = w3; n = 2560; break;
        case 51: src = w4; n = 5120; break;
        default: src = wo; n = 64;   break;
    }
    float m = 0.f;
    for (int i = tid; i < n; i += 256) m = fmaxf(m, fabsf(ldE(src, i, f32)));
    red[tid] = m;
    __syncthreads();
    for (int s = 128; s > 0; s >>= 1) {
        if (tid < s) red[tid] = fmaxf(red[tid], red[tid + s]);
        __syncthreads();
    }
    float sc = red[0] / 127.f;

    if (which == 48) {
        if (tid < 64) wsf[tid] = qv(src, tid, sc, f32);
    } else if (which == 52) {
        if (tid < 64) wsf[224 + tid] = qv(src, tid, sc, f32);
    } else if (which == 49) {       // conv2 A-frags: k = dk*16+ci, pad dk=3
        for (int e = tid; e < 1024; e += 256) {
            int c = e >> 9, l = (e >> 3) & 63, j = e & 7;
            int mm = l & 15;
            int k = c * 32 + ((l >> 4) & 3) * 8 + j;
            int dk = k >> 4, ci = k & 15;
            float v = (dk < 3) ? qv(src, (mm * 16 + ci) * 3 + dk, sc, f32) : 0.f;
            wh[0 + e] = (h16)v;
        }
    } else if (which == 50) {       // conv3 A-frags: k = dk*16+ci, dk = chunk
        for (int e = tid; e < 2560; e += 256) {
            int c = e >> 9, l = (e >> 3) & 63, j = e & 7;
            int mm = l & 31;
            int ci = ((l >> 5) & 1) * 8 + j;
            wh[1024 + e] = (h16)qv(src, (mm * 16 + ci) * 5 + c, sc, f32);
        }
    } else {                        // conv4 A-frags: k = dk*32+ci
        for (int e = tid; e < 5120; e += 256) {
            int c = e >> 9, l = (e >> 3) & 63, j = e & 7;
            int mm = l & 31;
            int k = c * 16 + ((l >> 5) & 1) * 8 + j;
            int dk = k >> 5, ci = k & 31;
            wh[3584 + e] = (h16)qv(src, (mm * 32 + ci) * 5 + dk, sc, f32);
        }
    }
}

// Chunked activation layouts: [k-group][pos][8 h16] -> all MFMA B-fragment
// reads are lane-contiguous 16B (zero bank conflicts).
//   U (per wave, 2112 h16): act1/pooled as 2 groups x 132 rows (stride 1056);
//                           act4 as 4 groups x 56 rows (stride 448)
//   V (per wave, 2208 h16): act2 as 2 groups x 126 rows (stride 1008);
//                           act3 as 4 groups x 69 rows (stride 552)
//   flatb rows 872 h16 (s-stride = 20 banks -> disjoint bank groups), chunk
//   order phys = g*27 + pos (pool2 writes contiguous).
__global__ void __launch_bounds__(256, 3) qcnn_main(
    const void* __restrict__ x,      // [B][2][128] bf16 or f32
    const float* __restrict__ wsf,
    void* __restrict__ out)          // [B]
{
    const int f32flag = ((const int*)wsf)[290];
    const float* qw1f = wsf;
    const float* fb1g = wsf + 64;
    const h16*  wh  = (const h16*)(wsf + 292);
    const h16*  F2g = wh;
    const h16*  F3g = wh + 1024;
    const h16*  F4g = wh + 3584;
    const h16*  FDg = wh + 8704;

    __shared__ __align__(16) h16 Uall[4][2112];
    __shared__ __align__(16) h16 Vall[4][2208];
    __shared__ __align__(16) h16 flatb[8][872];
    __shared__ float red[256];

    int tid  = threadIdx.x;
    int lane = tid & 63;
    int w    = __builtin_amdgcn_readfirstlane(tid >> 6);
    int n16  = lane & 15, kg16 = (lane >> 4) & 3;
    int n32  = lane & 31, kg32 = (lane >> 5) & 1;
    int o16  = kg16 * 4;
    h16* U = Uall[w];
    h16* V = Vall[w];
    long b0 = (long)blockIdx.x * 8;

    // loop-invariant A fragments (16B/lane coalesced)
    h16x8 a2[2], a3[5], a4[10];
#pragma unroll
    for (int c = 0; c < 2; ++c)  a2[c] = *(const h16x8*)&F2g[c * 512 + lane * 8];
#pragma unroll
    for (int c = 0; c < 5; ++c)  a3[c] = *(const h16x8*)&F3g[c * 512 + lane * 8];
#pragma unroll
    for (int c = 0; c < 10; ++c) a4[c] = *(const h16x8*)&F4g[c * 512 + lane * 8];
    f32x4 b2v = *(const f32x4*)&wsf[80 + o16];

    for (int it = 0; it < 2; ++it) {
        int slot = w * 2 + it;
        long sb = (b0 + slot) * 256;

        // ---- conv1 (VALU): x[2][128] -> act1 U[2g][127] ----
        LDS_FENCE();
        float xl[2][4];
#pragma unroll
        for (int ci = 0; ci < 2; ++ci) {
            int rb = ci * 128;
            xl[ci][0] = ldE(x, sb + rb + lane, f32flag);
            xl[ci][1] = ldE(x, sb + rb + lane + 1, f32flag);
            xl[ci][2] = ldE(x, sb + rb + 64 + lane, f32flag);
            xl[ci][3] = ldE(x, sb + rb + 64 + ((lane + 1) & 63), f32flag);
        }
        h16x8 ra, rbv, rc, rd;
#pragma unroll
        for (int co = 0; co < 16; ++co) {
            float w00 = qw1f[co*4+0], w01 = qw1f[co*4+1], w10 = qw1f[co*4+2], w11 = qw1f[co*4+3];
            float bb = fb1g[co];
            float v0 = bb + xl[0][0]*w00 + xl[0][1]*w01 + xl[1][0]*w10 + xl[1][1]*w11;
            float v1 = bb + xl[0][2]*w00 + xl[0][3]*w01 + xl[1][2]*w10 + xl[1][3]*w11;
            v0 = lrelu(v0); v1 = lrelu(v1);
            if (co < 8) { ra[co] = (h16)v0; rc[co] = (h16)v1; }
            else        { rbv[co-8] = (h16)v0; rd[co-8] = (h16)v1; }
        }
        *(h16x8*)&U[lane * 8]        = ra;    // g0, pos lane
        *(h16x8*)&U[1056 + lane * 8] = rbv;   // g1
        if (lane < 63) {
            *(h16x8*)&U[(64 + lane) * 8]        = rc;
            *(h16x8*)&U[1056 + (64 + lane) * 8] = rd;
        }
        LDS_FENCE();

        // ---- conv2 (16x16x32): act1 -> act2 V[2g][125] ----
#pragma unroll
        for (int t = 0; t < 8; ++t) {
            int n = t * 16 + n16;
            f32x4 acc = {0.f, 0.f, 0.f, 0.f};
#pragma unroll
            for (int c = 0; c < 2; ++c) {
                int k0 = c * 32 + kg16 * 8;
                int dk = k0 >> 4, g = (k0 & 15) >> 3;
                h16x8 bfr = *(const h16x8*)&U[g * 1056 + (n + dk) * 8];
                acc = __builtin_amdgcn_mfma_f32_16x16x32_f16(a2[c], bfr, acc, 0, 0, 0);
            }
            if (n < 125) {
                uint2 p = pack4(lrelu(acc[0] + b2v[0]), lrelu(acc[1] + b2v[1]),
                                lrelu(acc[2] + b2v[2]), lrelu(acc[3] + b2v[3]));
                *(uint2*)&V[(o16 >> 3) * 1008 + n * 8 + (o16 & 7)] = p;
            }
        }
        LDS_FENCE();

        // ---- pool1: act2 -> pooled U[2g][62] ----
        if (lane < 62) {
#pragma unroll
            for (int g = 0; g < 2; ++g) {
                h16x8 pa = *(const h16x8*)&V[g * 1008 + (2 * lane) * 8];
                h16x8 pb = *(const h16x8*)&V[g * 1008 + (2 * lane + 1) * 8];
                h16x8 mm;
#pragma unroll
                for (int e = 0; e < 8; ++e) mm[e] = pa[e] > pb[e] ? pa[e] : pb[e];
                *(h16x8*)&U[g * 1056 + lane * 8] = mm;
            }
        }
        LDS_FENCE();

        // ---- conv3 (32x32x16): pooled -> act3 V[4g][58] ----
#pragma unroll
        for (int t = 0; t < 2; ++t) {
            int n = t * 32 + n32;
            f32x16 acc = {0.f,0.f,0.f,0.f,0.f,0.f,0.f,0.f,0.f,0.f,0.f,0.f,0.f,0.f,0.f,0.f};
#pragma unroll
            for (int c = 0; c < 5; ++c) {
                h16x8 bfr = *(const h16x8*)&U[kg32 * 1056 + (n + c) * 8];
                acc = __builtin_amdgcn_mfma_f32_32x32x16_f16(a3[c], bfr, acc, 0, 0, 0);
            }
#pragma unroll
            for (int g = 0; g < 4; ++g) {
                int r0 = 8 * g + 4 * kg32;
                f32x4 bv = *(const f32x4*)&wsf[96 + r0];
                if (n < 58) {
                    uint2 p = pack4(lrelu(acc[4*g+0] + bv[0]), lrelu(acc[4*g+1] + bv[1]),
                                    lrelu(acc[4*g+2] + bv[2]), lrelu(acc[4*g+3] + bv[3]));
                    *(uint2*)&V[g * 552 + n * 8 + 4 * kg32] = p;
                }
            }
        }
        LDS_FENCE();

        // ---- conv4 (32x32x16): act3 -> act4 U[4g][54] ----
#pragma unroll
        for (int t = 0; t < 2; ++t) {
            int n = t * 32 + n32;
            f32x16 acc = {0.f,0.f,0.f,0.f,0.f,0.f,0.f,0.f,0.f,0.f,0.f,0.f,0.f,0.f,0.f,0.f};
#pragma unroll
            for (int c = 0; c < 10; ++c) {
                int k0 = c * 16 + kg32 * 8;
                int dk = k0 >> 5, g = (k0 >> 3) & 3;
                h16x8 bfr = *(const h16x8*)&V[g * 552 + (n + dk) * 8];
                acc = __builtin_amdgcn_mfma_f32_32x32x16_f16(a4[c], bfr, acc, 0, 0, 0);
            }
#pragma unroll
            for (int g = 0; g < 4; ++g) {
                int r0 = 8 * g + 4 * kg32;
                f32x4 bv = *(const f32x4*)&wsf[128 + r0];
                if (n < 54) {
                    uint2 p = pack4(lrelu(acc[4*g+0] + bv[0]), lrelu(acc[4*g+1] + bv[1]),
                                    lrelu(acc[4*g+2] + bv[2]), lrelu(acc[4*g+3] + bv[3]));
                    *(uint2*)&U[g * 448 + n * 8 + 4 * kg32] = p;
                }
            }
        }
        LDS_FENCE();

        // ---- pool2 + flatten: act4 -> flatb[slot], phys chunk = g*27 + pos ----
        if (lane < 27) {
#pragma unroll
            for (int g = 0; g < 4; ++g) {
                h16x8 pa = *(const h16x8*)&U[g * 448 + (2 * lane) * 8];
                h16x8 pb = *(const h16x8*)&U[g * 448 + (2 * lane + 1) * 8];
                h16x8 mm;
#pragma unroll
                for (int e = 0; e < 8; ++e) mm[e] = pa[e] > pb[e] ? pa[e] : pb[e];
                *(h16x8*)&flatb[slot][(g * 27 + lane) * 8] = mm;
            }
        }
    }
    __syncthreads();

    // ---- dense (16x16x32): flatb[8][864] @ FD, wave w = m-tile ----
    f32x4 dacc = {0.f, 0.f, 0.f, 0.f};
    for (int c = 0; c < 27; ++c) {
        h16x8 aw = *(const h16x8*)&FDg[((w * 27 + c) * 64 + lane) * 8];
        h16x8 bh = *(const h16x8*)&flatb[lane & 7][(kg16 * 27 + c) * 8];
        dacc = __builtin_amdgcn_mfma_f32_16x16x32_f16(aw, bh, dacc, 0, 0, 0);
    }
    int o0g = w * 16 + o16;
    f32x4 bdv = *(const f32x4*)&wsf[160 + o0g];
    f32x4 qov = *(const f32x4*)&wsf[224 + o0g];
    float part = 0.f;
#pragma unroll
    for (int q = 0; q < 4; ++q) part += lrelu(dacc[q] + bdv[q]) * qov[q];
    red[tid] = part;
    __syncthreads();
    if (tid < 8) {
        float y = wsf[288];
#pragma unroll
        for (int g = 0; g < 16; ++g) y += red[(g >> 2) * 64 + (g & 3) * 16 + tid];
        if (f32flag) ((float*)out)[b0 + tid] = y;
        else         ((bf16*)out)[b0 + tid] = __float2bfloat16(y);
    }
}

extern "C" void kernel_launch(void* const* d_in, const int* in_sizes, int n_in,
                              void* d_out, int out_size, void* d_ws, size_t ws_size,
                              hipStream_t stream) {
    const void* x  = d_in[0];
    const void* w1 = d_in[1];
    const void* b1 = d_in[2];
    const void* w2 = d_in[3];
    const void* b2 = d_in[4];
    const void* w3 = d_in[5];
    const void* b3 = d_in[6];
    const void* w4 = d_in[7];
    const void* b4 = d_in[8];
    const void* wd = d_in[9];
    const void* bd = d_in[10];
    const void* wo = d_in[11];
    const void* bo = d_in[12];
    float* wsf = (float*)d_ws;

    int B = in_sizes[0] / 256;            // 32768
    quant_prep<<<54, 256, 0, stream>>>((const unsigned short*)x,
                                       w1, w2, w3, w4, wd, wo,
                                       b1, b2, b3, b4, bd, bo, wsf);
    qcnn_main<<<B / 8, 256, 0, stream>>>(x, wsf, d_out);
}